// Round 7
// baseline (753.485 us; speedup 1.0000x reference)
//
#include <hip/hip_runtime.h>
#include <hip/hip_bf16.h>
#include <cstddef>

// Problem constants (fixed by the reference).
#define B_   16
#define N_   1024
#define E_   768
#define H_   8
#define D_   96          // E_/H_
#define HID_ 1536        // 2*E_
#define ROWS (B_ * N_)   // 16384
#define SCALE_  0.03608439182435161f   // 1/sqrt(768)
#define QSCALE_ 0.052058774f           // SCALE_ * log2(e): softmax in exp2 domain

typedef __attribute__((ext_vector_type(8))) short bf16x8;
typedef __attribute__((ext_vector_type(4))) float f32x4;

__device__ __forceinline__ unsigned short f2bf(float f) {
    union { float f; unsigned int u; } c; c.f = f;
    unsigned int u = c.u + 0x7FFFu + ((c.u >> 16) & 1u);  // RNE
    return (unsigned short)(u >> 16);
}

__device__ __forceinline__ unsigned short f2bf_hw(float f) {
    union { __hip_bfloat16 h; unsigned short u; } c;
    c.h = __float2bfloat16(f);
    return c.u;
}

__device__ __forceinline__ void gload16(const void* g, void* l) {
    __builtin_amdgcn_global_load_lds(
        (const __attribute__((address_space(1))) unsigned int*)g,
        (__attribute__((address_space(3))) unsigned int*)l, 16, 0, 0);
}

__device__ __forceinline__ float gelu_exact(float x) {
    return 0.5f * x * (1.0f + erff(x * 0.7071067811865475f));
}

// ---------------------------------------------------------------------------
// Weight convert+transpose: fp32 W[K][N] -> bf16 Wt[N][K]. 32x32 tiles.
// ---------------------------------------------------------------------------
__global__ __launch_bounds__(256) void wcvt_kernel(const float* __restrict__ W,
                                                   unsigned short* __restrict__ Wt,
                                                   int K, int N) {
    __shared__ float t[32][33];
    int n0 = blockIdx.x * 32, k0 = blockIdx.y * 32;
    int tr = threadIdx.x >> 3;
    int tc = (threadIdx.x & 7) * 4;
    float4 v = *(const float4*)&W[(size_t)(k0 + tr) * N + n0 + tc];
    t[tr][tc + 0] = v.x; t[tr][tc + 1] = v.y; t[tr][tc + 2] = v.z; t[tr][tc + 3] = v.w;
    __syncthreads();
    ushort4 o;
    o.x = f2bf(t[tc + 0][tr]);
    o.y = f2bf(t[tc + 1][tr]);
    o.z = f2bf(t[tc + 2][tr]);
    o.w = f2bf(t[tc + 3][tr]);
    *(ushort4*)&Wt[(size_t)(n0 + tr) * K + k0 + tc] = o;
}

// ---------------------------------------------------------------------------
// Fused LayerNorm -> bf16. One block per row of 768.
// ---------------------------------------------------------------------------
__global__ __launch_bounds__(256) void ln_fused_kernel(const float* __restrict__ x,
                                                       const float* __restrict__ g,
                                                       const float* __restrict__ beta,
                                                       unsigned short* __restrict__ out) {
    int row = blockIdx.x;
    int tid = threadIdx.x;
    const float* xr = x + (size_t)row * E_;
    float v0 = xr[tid];
    float v1 = xr[tid + 256];
    float v2 = xr[tid + 512];
    float s  = v0 + v1 + v2;
    float s2 = v0 * v0 + v1 * v1 + v2 * v2;
#pragma unroll
    for (int off = 32; off > 0; off >>= 1) {
        s  += __shfl_down(s, off);
        s2 += __shfl_down(s2, off);
    }
    __shared__ float sb[8];
    __shared__ float stats[2];
    int lane = tid & 63, wid = tid >> 6;
    if (lane == 0) { sb[wid] = s; sb[4 + wid] = s2; }
    __syncthreads();
    if (tid == 0) {
        float S  = sb[0] + sb[1] + sb[2] + sb[3];
        float S2 = sb[4] + sb[5] + sb[6] + sb[7];
        float m = S * (1.0f / E_);
        float var = S2 * (1.0f / E_) - m * m;
        stats[0] = m;
        stats[1] = rsqrtf(var + 1e-5f);
    }
    __syncthreads();
    float mean = stats[0], rstd = stats[1];
    unsigned short* orow = out + (size_t)row * E_;
    orow[tid]       = f2bf((v0 - mean) * rstd * g[tid]       + beta[tid]);
    orow[tid + 256] = f2bf((v1 - mean) * rstd * g[tid + 256] + beta[tid + 256]);
    orow[tid + 512] = f2bf((v2 - mean) * rstd * g[tid + 512] + beta[tid + 512]);
}

// ---------------------------------------------------------------------------
// bf16 MFMA GEMM (m97 structure) — unchanged.
// ---------------------------------------------------------------------------
template<int MODE>
__global__ __launch_bounds__(256) void bgemm_kernel(
    const unsigned short* __restrict__ A, const unsigned short* __restrict__ Wt,
    const float* __restrict__ bias,
    const float* R, float* C, unsigned short* Cb,
    unsigned short* qo, unsigned short* ko, unsigned short* vo,
    int M, int N, int K)
{
    __shared__ __align__(16) unsigned short As[128 * 32];
    __shared__ __align__(16) unsigned short Bs[128 * 32];
    const int tid = threadIdx.x;
    const int l = tid & 63, w = tid >> 6;
    const int bm = blockIdx.y * 128, bn = blockIdx.x * 128;
    const int wr = (w >> 1) * 64, wc = (w & 1) * 64;
    const int l15 = l & 15, l4 = l >> 4;

    const int srow = w * 16 + (l >> 2);
    const int scol = (l & 3) * 8;
    const unsigned short* Ag = A  + (size_t)(bm + srow) * K + scol;
    const unsigned short* Wg = Wt + (size_t)(bn + srow) * K + scol;
    unsigned short* AsW = As + w * 512;
    unsigned short* BsW = Bs + w * 512;

    f32x4 acc[4][4] = {};

    for (int k0 = 0; k0 < K; k0 += 32) {
        __syncthreads();
        gload16(Ag + k0,                  AsW);
        gload16(Ag + (size_t)64 * K + k0, AsW + 2048);
        gload16(Wg + k0,                  BsW);
        gload16(Wg + (size_t)64 * K + k0, BsW + 2048);
        __syncthreads();
        bf16x8 af[4], bfr[4];
#pragma unroll
        for (int mi = 0; mi < 4; ++mi)
            af[mi] = *(const bf16x8*)&As[(wr + mi * 16 + l15) * 32 + l4 * 8];
#pragma unroll
        for (int ni = 0; ni < 4; ++ni)
            bfr[ni] = *(const bf16x8*)&Bs[(wc + ni * 16 + l15) * 32 + l4 * 8];
#pragma unroll
        for (int mi = 0; mi < 4; ++mi)
#pragma unroll
            for (int ni = 0; ni < 4; ++ni)
                acc[mi][ni] = __builtin_amdgcn_mfma_f32_16x16x32_bf16(
                    af[mi], bfr[ni], acc[mi][ni], 0, 0, 0);
    }

    const int r0 = bm + wr + l4 * 4;
    const int c0 = bn + wc + l15;
    float bv[4];
#pragma unroll
    for (int ni = 0; ni < 4; ++ni) bv[ni] = bias[c0 + ni * 16];

#pragma unroll
    for (int mi = 0; mi < 4; ++mi) {
#pragma unroll
        for (int r = 0; r < 4; ++r) {
            int row = r0 + mi * 16 + r;
            if constexpr (MODE == 0) {
                size_t base = (size_t)row * N;
#pragma unroll
                for (int ni = 0; ni < 4; ++ni) {
                    size_t idx = base + c0 + ni * 16;
                    C[idx] = acc[mi][ni][r] + bv[ni] + R[idx];
                }
            } else if constexpr (MODE == 1) {
                size_t base = (size_t)row * N;
#pragma unroll
                for (int ni = 0; ni < 4; ++ni) {
                    size_t idx = base + c0 + ni * 16;
                    Cb[idx] = f2bf(gelu_exact(acc[mi][ni][r] + bv[ni]));
                }
            } else {
                int b = row >> 10, ntok = row & (N_ - 1);
#pragma unroll
                for (int ni = 0; ni < 4; ++ni) {
                    int n = c0 + ni * 16;
                    int e = n / 3, t = n - e * 3;
                    int hh = e / D_, dd = e - hh * D_;
                    float cval = acc[mi][ni][r] + bv[ni];
                    size_t bh = (size_t)(b * H_ + hh);
                    if (t == 0)      qo[(bh * N_ + ntok) * D_ + dd] = f2bf(cval * QSCALE_);
                    else if (t == 1) ko[(bh * N_ + ntok) * D_ + dd] = f2bf(cval);
                    else             vo[(bh * D_ + dd) * N_ + ntok] = f2bf(cval);
                }
            }
        }
    }
}

// ---------------------------------------------------------------------------
// Flash attention v2b: identical to round-5 v2 EXCEPT launch bounds.
// Round-6 evidence: __launch_bounds__(256,4) forced VGPR=64 -> scratch spill
// (WRITE_SIZE 25->811 MB, dur 188->259). LDS=36.9KB already caps occupancy
// at 4 blocks/CU; let the register allocator have what it needs.
// ---------------------------------------------------------------------------
#define QT  64
#define KVT 64
#define NT  (N_ / KVT)

__global__ __launch_bounds__(256) void fattn_kernel(
    const unsigned short* __restrict__ qg, const unsigned short* __restrict__ kg,
    const unsigned short* __restrict__ vtg, unsigned short* __restrict__ out) {
    int bh = blockIdx.y;
    int b = bh >> 3, h = bh & 7;
    int q0 = blockIdx.x * QT;
    int tid = threadIdx.x;
    int l = tid & 63, w = tid >> 6;
    int q16 = l & 15, g = l >> 4;
    int hi2 = (l >> 5) & 1;
    const int swz = (q16 & 7) << 3;          // frag-read swizzle (ushort idx)

    __shared__ __align__(16) unsigned short Qs[QT * D_];    // 12 KB, swizzled
    __shared__ __align__(16) unsigned short Ks[KVT * D_];   // 12 KB, swizzled
    __shared__ __align__(16) unsigned short Vts[D_ * KVT];  // 12 KB, swizzled

    // staging maps
    const int krow = tid >> 2, kc8 = (tid & 3) * 24;   // K/Q: 64 rows x 96
    const int vrow0 = tid >> 3, vc8 = (tid & 7) * 8;   // V^T: 96 rows x 64

    // ---- stage Q tile once (swizzled) ----
    {
        const uint4* src = (const uint4*)(qg + ((size_t)bh * N_ + q0 + krow) * D_ + kc8);
        int sw = (krow & 7) << 3;
#pragma unroll
        for (int i = 0; i < 3; ++i)
            *(uint4*)&Qs[(krow * D_ + kc8 + i * 8) ^ sw] = src[i];
    }
    __syncthreads();

    bf16x8 qf[3];
#pragma unroll
    for (int dc = 0; dc < 3; ++dc)
        qf[dc] = *(const bf16x8*)&Qs[((w * 16 + q16) * D_ + dc * 32 + g * 8) ^ swz];

    // ---- prologue: load kv-tile 0 into regs ----
    uint4 kreg[3], vreg[3];
    {
        const uint4* ks = (const uint4*)(kg + ((size_t)bh * N_ + krow) * D_ + kc8);
#pragma unroll
        for (int i = 0; i < 3; ++i) kreg[i] = ks[i];
#pragma unroll
        for (int p = 0; p < 3; ++p)
            vreg[p] = *(const uint4*)(vtg + ((size_t)bh * D_ + vrow0 + p * 32) * N_ + vc8);
    }

    float m_run = -INFINITY, l_run = 0.f;
    f32x4 oacc[6] = {};

    for (int kt = 0; kt < NT; ++kt) {
        __syncthreads();   // previous tile's compute done
        // ---- write staged regs -> LDS (swizzled) ----
        {
            int sw = (krow & 7) << 3;
#pragma unroll
            for (int i = 0; i < 3; ++i)
                *(uint4*)&Ks[(krow * D_ + kc8 + i * 8) ^ sw] = kreg[i];
#pragma unroll
            for (int p = 0; p < 3; ++p) {
                int row = vrow0 + p * 32;
                *(uint4*)&Vts[(row * KVT + vc8) ^ ((row & 7) << 3)] = vreg[p];
            }
        }
        __syncthreads();   // tile ready
        // ---- issue next tile's global loads (overlap with compute) ----
        if (kt + 1 < NT) {
            const uint4* ks = (const uint4*)(kg + ((size_t)bh * N_ + (kt + 1) * KVT + krow) * D_ + kc8);
#pragma unroll
            for (int i = 0; i < 3; ++i) kreg[i] = ks[i];
#pragma unroll
            for (int p = 0; p < 3; ++p)
                vreg[p] = *(const uint4*)(vtg + ((size_t)bh * D_ + vrow0 + p * 32) * N_ + (kt + 1) * KVT + vc8);
        }

        // ---- QK^T (swapped): lane holds S^T[kv=sub*16+g*4+r][q=q16] ----
        f32x4 sacc[4] = {};
#pragma unroll
        for (int sub = 0; sub < 4; ++sub)
#pragma unroll
            for (int dc = 0; dc < 3; ++dc) {
                bf16x8 af = *(const bf16x8*)&Ks[((sub * 16 + q16) * D_ + dc * 32 + g * 8) ^ swz];
                sacc[sub] = __builtin_amdgcn_mfma_f32_16x16x32_bf16(af, qf[dc], sacc[sub], 0, 0, 0);
            }

        // ---- online softmax, exp2 domain (log2e folded into q) ----
        float pmax = -INFINITY;
#pragma unroll
        for (int s = 0; s < 4; ++s)
#pragma unroll
            for (int r = 0; r < 4; ++r) pmax = fmaxf(pmax, sacc[s][r]);
        pmax = fmaxf(pmax, __shfl_xor(pmax, 16));
        pmax = fmaxf(pmax, __shfl_xor(pmax, 32));
        if (!__all(pmax - m_run <= 11.0f)) {   // defer-max (T13)
            float m_new = fmaxf(m_run, pmax);
            float fac = exp2f(m_run - m_new);
#pragma unroll
            for (int d = 0; d < 6; ++d)
#pragma unroll
                for (int r = 0; r < 4; ++r) oacc[d][r] *= fac;
            l_run *= fac;
            m_run = m_new;
        }
        float pe[4][4];
        float rs = 0.f;
#pragma unroll
        for (int s = 0; s < 4; ++s)
#pragma unroll
            for (int r = 0; r < 4; ++r) {
                pe[s][r] = exp2f(sacc[s][r] - m_run);
                rs += pe[s][r];
            }
        rs += __shfl_xor(rs, 16);
        rs += __shfl_xor(rs, 32);
        l_run += rs;

        // ---- pack P to bf16 pairs, shuffle u32s into PV B-frag layout ----
        unsigned int pk[4][2];
#pragma unroll
        for (int s = 0; s < 4; ++s)
#pragma unroll
            for (int j = 0; j < 2; ++j)
                pk[s][j] = (unsigned)f2bf_hw(pe[s][2 * j]) |
                           ((unsigned)f2bf_hw(pe[s][2 * j + 1]) << 16);
        union { unsigned int u[4]; bf16x8 v; } pfu[2];
#pragma unroll
        for (int c = 0; c < 2; ++c)
#pragma unroll
            for (int j = 0; j < 4; ++j) {
                int gsrc = (g & 1) * 2 + (j >> 1);
                int src = q16 + (gsrc << 4);
                unsigned a = (unsigned)__shfl((int)pk[c * 2][j & 1], src);
                unsigned bb = (unsigned)__shfl((int)pk[c * 2 + 1][j & 1], src);
                pfu[c].u[j] = hi2 ? bb : a;
            }

        // ---- PV: O^T[dsub] += V^T(16d x 32kv) * P^T(32kv x 16q) ----
#pragma unroll
        for (int dsub = 0; dsub < 6; ++dsub)
#pragma unroll
            for (int c = 0; c < 2; ++c) {
                bf16x8 vf = *(const bf16x8*)&Vts[((dsub * 16 + q16) * KVT + c * 32 + g * 8) ^ swz];
                oacc[dsub] = __builtin_amdgcn_mfma_f32_16x16x32_bf16(vf, pfu[c].v, oacc[dsub], 0, 0, 0);
            }
    }

    // ---- epilogue ----
    float inv = 1.0f / l_run;
    int qrow = q0 + w * 16 + q16;
    size_t base = ((size_t)(b * N_ + qrow)) * E_ + h * D_;
#pragma unroll
    for (int dsub = 0; dsub < 6; ++dsub)
#pragma unroll
        for (int r = 0; r < 4; ++r)
            out[base + dsub * 16 + g * 4 + r] = f2bf_hw(oacc[dsub][r] * inv);
}

// ---------------------------------------------------------------------------
// Orchestration (identical to round 4/5).
// ---------------------------------------------------------------------------
extern "C" void kernel_launch(void* const* d_in, const int* in_sizes, int n_in,
                              void* d_out, int out_size, void* d_ws, size_t ws_size,
                              hipStream_t stream) {
    const float* x      = (const float*)d_in[0];
    const float* ln1_g  = (const float*)d_in[1];
    const float* ln1_b  = (const float*)d_in[2];
    const float* qkv_w  = (const float*)d_in[3];
    const float* qkv_b  = (const float*)d_in[4];
    const float* proj_w = (const float*)d_in[5];
    const float* proj_b = (const float*)d_in[6];
    const float* ln2_g  = (const float*)d_in[7];
    const float* ln2_b  = (const float*)d_in[8];
    const float* ff1_w  = (const float*)d_in[9];
    const float* ff1_b  = (const float*)d_in[10];
    const float* ff2_w  = (const float*)d_in[11];
    const float* ff2_b  = (const float*)d_in[12];
    float* out = (float*)d_out;
    float* ws  = (float*)d_ws;

    const size_t S = (size_t)ROWS * E_ / 2;
    unsigned short* qkv_wt = (unsigned short*)ws;
    unsigned short* proj_wt = qkv_wt + (size_t)3 * E_ * E_;
    unsigned short* ff1_wt  = proj_wt + (size_t)E_ * E_;
    unsigned short* ff2_wt  = ff1_wt + (size_t)HID_ * E_;
    float* Rb = ws + 2359296;
    unsigned short* h16   = (unsigned short*)(Rb);
    unsigned short* q16   = (unsigned short*)(Rb + S);
    unsigned short* k16   = (unsigned short*)(Rb + 2 * S);
    unsigned short* vt16  = (unsigned short*)(Rb + 3 * S);
    unsigned short* attnb = h16;
    unsigned short* h16b  = q16;
    unsigned short* ffh   = k16;
    float* x1 = out;

    wcvt_kernel<<<dim3(3 * E_ / 32, E_ / 32), 256, 0, stream>>>(qkv_w, qkv_wt, E_, 3 * E_);
    wcvt_kernel<<<dim3(E_ / 32, E_ / 32), 256, 0, stream>>>(proj_w, proj_wt, E_, E_);
    wcvt_kernel<<<dim3(HID_ / 32, E_ / 32), 256, 0, stream>>>(ff1_w, ff1_wt, E_, HID_);
    wcvt_kernel<<<dim3(E_ / 32, HID_ / 32), 256, 0, stream>>>(ff2_w, ff2_wt, HID_, E_);
    ln_fused_kernel<<<ROWS, 256, 0, stream>>>(x, ln1_g, ln1_b, h16);
    bgemm_kernel<2><<<dim3(3 * E_ / 128, ROWS / 128), 256, 0, stream>>>(
        h16, qkv_wt, qkv_b, nullptr, nullptr, nullptr, q16, k16, vt16,
        ROWS, 3 * E_, E_);
    fattn_kernel<<<dim3(N_ / QT, B_ * H_), 256, 0, stream>>>(q16, k16, vt16, attnb);
    bgemm_kernel<0><<<dim3(E_ / 128, ROWS / 128), 256, 0, stream>>>(
        attnb, proj_wt, proj_b, x, x1, nullptr, nullptr, nullptr, nullptr,
        ROWS, E_, E_);
    ln_fused_kernel<<<ROWS, 256, 0, stream>>>(x1, ln2_g, ln2_b, h16b);
    bgemm_kernel<1><<<dim3(HID_ / 128, ROWS / 128), 256, 0, stream>>>(
        h16b, ff1_wt, ff1_b, nullptr, nullptr, ffh, nullptr, nullptr, nullptr,
        ROWS, HID_, E_);
    bgemm_kernel<0><<<dim3(E_ / 128, ROWS / 128), 256, 0, stream>>>(
        ffh, ff2_wt, ff2_b, x1, out, nullptr, nullptr, nullptr, nullptr,
        ROWS, E_, HID_);
}

// Round 8
// 623.399 us; speedup vs baseline: 1.2087x; 1.2087x over previous
//
#include <hip/hip_runtime.h>
#include <hip/hip_bf16.h>
#include <cstddef>

// Problem constants (fixed by the reference).
#define B_   16
#define N_   1024
#define E_   768
#define H_   8
#define D_   96          // E_/H_
#define HID_ 1536        // 2*E_
#define ROWS (B_ * N_)   // 16384
#define SCALE_  0.03608439182435161f   // 1/sqrt(768)
#define QSCALE_ 0.052058774f           // SCALE_ * log2(e): softmax in exp2 domain

typedef __attribute__((ext_vector_type(8))) short bf16x8;
typedef __attribute__((ext_vector_type(4))) float f32x4;

__device__ __forceinline__ unsigned short f2bf(float f) {
    union { float f; unsigned int u; } c; c.f = f;
    unsigned int u = c.u + 0x7FFFu + ((c.u >> 16) & 1u);  // RNE
    return (unsigned short)(u >> 16);
}

__device__ __forceinline__ unsigned short f2bf_hw(float f) {
    union { __hip_bfloat16 h; unsigned short u; } c;
    c.h = __float2bfloat16(f);
    return c.u;
}

__device__ __forceinline__ void gload16(const void* g, void* l) {
    __builtin_amdgcn_global_load_lds(
        (const __attribute__((address_space(1))) unsigned int*)g,
        (__attribute__((address_space(3))) unsigned int*)l, 16, 0, 0);
}

__device__ __forceinline__ float gelu_exact(float x) {
    return 0.5f * x * (1.0f + erff(x * 0.7071067811865475f));
}

// ---------------------------------------------------------------------------
// Weight convert+transpose: fp32 W[K][N] -> bf16 Wt[N][K]. 32x32 tiles.
// ---------------------------------------------------------------------------
__global__ __launch_bounds__(256) void wcvt_kernel(const float* __restrict__ W,
                                                   unsigned short* __restrict__ Wt,
                                                   int K, int N) {
    __shared__ float t[32][33];
    int n0 = blockIdx.x * 32, k0 = blockIdx.y * 32;
    int tr = threadIdx.x >> 3;
    int tc = (threadIdx.x & 7) * 4;
    float4 v = *(const float4*)&W[(size_t)(k0 + tr) * N + n0 + tc];
    t[tr][tc + 0] = v.x; t[tr][tc + 1] = v.y; t[tr][tc + 2] = v.z; t[tr][tc + 3] = v.w;
    __syncthreads();
    ushort4 o;
    o.x = f2bf(t[tc + 0][tr]);
    o.y = f2bf(t[tc + 1][tr]);
    o.z = f2bf(t[tc + 2][tr]);
    o.w = f2bf(t[tc + 3][tr]);
    *(ushort4*)&Wt[(size_t)(n0 + tr) * K + k0 + tc] = o;
}

// ---------------------------------------------------------------------------
// Fused LayerNorm -> bf16. One block per row of 768.
// ---------------------------------------------------------------------------
__global__ __launch_bounds__(256) void ln_fused_kernel(const float* __restrict__ x,
                                                       const float* __restrict__ g,
                                                       const float* __restrict__ beta,
                                                       unsigned short* __restrict__ out) {
    int row = blockIdx.x;
    int tid = threadIdx.x;
    const float* xr = x + (size_t)row * E_;
    float v0 = xr[tid];
    float v1 = xr[tid + 256];
    float v2 = xr[tid + 512];
    float s  = v0 + v1 + v2;
    float s2 = v0 * v0 + v1 * v1 + v2 * v2;
#pragma unroll
    for (int off = 32; off > 0; off >>= 1) {
        s  += __shfl_down(s, off);
        s2 += __shfl_down(s2, off);
    }
    __shared__ float sb[8];
    __shared__ float stats[2];
    int lane = tid & 63, wid = tid >> 6;
    if (lane == 0) { sb[wid] = s; sb[4 + wid] = s2; }
    __syncthreads();
    if (tid == 0) {
        float S  = sb[0] + sb[1] + sb[2] + sb[3];
        float S2 = sb[4] + sb[5] + sb[6] + sb[7];
        float m = S * (1.0f / E_);
        float var = S2 * (1.0f / E_) - m * m;
        stats[0] = m;
        stats[1] = rsqrtf(var + 1e-5f);
    }
    __syncthreads();
    float mean = stats[0], rstd = stats[1];
    unsigned short* orow = out + (size_t)row * E_;
    orow[tid]       = f2bf((v0 - mean) * rstd * g[tid]       + beta[tid]);
    orow[tid + 256] = f2bf((v1 - mean) * rstd * g[tid + 256] + beta[tid + 256]);
    orow[tid + 512] = f2bf((v2 - mean) * rstd * g[tid + 512] + beta[tid + 512]);
}

// ---------------------------------------------------------------------------
// bf16 MFMA GEMM (m97 structure) — unchanged.
// ---------------------------------------------------------------------------
template<int MODE>
__global__ __launch_bounds__(256) void bgemm_kernel(
    const unsigned short* __restrict__ A, const unsigned short* __restrict__ Wt,
    const float* __restrict__ bias,
    const float* R, float* C, unsigned short* Cb,
    unsigned short* qo, unsigned short* ko, unsigned short* vo,
    int M, int N, int K)
{
    __shared__ __align__(16) unsigned short As[128 * 32];
    __shared__ __align__(16) unsigned short Bs[128 * 32];
    const int tid = threadIdx.x;
    const int l = tid & 63, w = tid >> 6;
    const int bm = blockIdx.y * 128, bn = blockIdx.x * 128;
    const int wr = (w >> 1) * 64, wc = (w & 1) * 64;
    const int l15 = l & 15, l4 = l >> 4;

    const int srow = w * 16 + (l >> 2);
    const int scol = (l & 3) * 8;
    const unsigned short* Ag = A  + (size_t)(bm + srow) * K + scol;
    const unsigned short* Wg = Wt + (size_t)(bn + srow) * K + scol;
    unsigned short* AsW = As + w * 512;
    unsigned short* BsW = Bs + w * 512;

    f32x4 acc[4][4] = {};

    for (int k0 = 0; k0 < K; k0 += 32) {
        __syncthreads();
        gload16(Ag + k0,                  AsW);
        gload16(Ag + (size_t)64 * K + k0, AsW + 2048);
        gload16(Wg + k0,                  BsW);
        gload16(Wg + (size_t)64 * K + k0, BsW + 2048);
        __syncthreads();
        bf16x8 af[4], bfr[4];
#pragma unroll
        for (int mi = 0; mi < 4; ++mi)
            af[mi] = *(const bf16x8*)&As[(wr + mi * 16 + l15) * 32 + l4 * 8];
#pragma unroll
        for (int ni = 0; ni < 4; ++ni)
            bfr[ni] = *(const bf16x8*)&Bs[(wc + ni * 16 + l15) * 32 + l4 * 8];
#pragma unroll
        for (int mi = 0; mi < 4; ++mi)
#pragma unroll
            for (int ni = 0; ni < 4; ++ni)
                acc[mi][ni] = __builtin_amdgcn_mfma_f32_16x16x32_bf16(
                    af[mi], bfr[ni], acc[mi][ni], 0, 0, 0);
    }

    const int r0 = bm + wr + l4 * 4;
    const int c0 = bn + wc + l15;
    float bv[4];
#pragma unroll
    for (int ni = 0; ni < 4; ++ni) bv[ni] = bias[c0 + ni * 16];

#pragma unroll
    for (int mi = 0; mi < 4; ++mi) {
#pragma unroll
        for (int r = 0; r < 4; ++r) {
            int row = r0 + mi * 16 + r;
            if constexpr (MODE == 0) {
                size_t base = (size_t)row * N;
#pragma unroll
                for (int ni = 0; ni < 4; ++ni) {
                    size_t idx = base + c0 + ni * 16;
                    C[idx] = acc[mi][ni][r] + bv[ni] + R[idx];
                }
            } else if constexpr (MODE == 1) {
                size_t base = (size_t)row * N;
#pragma unroll
                for (int ni = 0; ni < 4; ++ni) {
                    size_t idx = base + c0 + ni * 16;
                    Cb[idx] = f2bf(gelu_exact(acc[mi][ni][r] + bv[ni]));
                }
            } else {
                int b = row >> 10, ntok = row & (N_ - 1);
#pragma unroll
                for (int ni = 0; ni < 4; ++ni) {
                    int n = c0 + ni * 16;
                    int e = n / 3, t = n - e * 3;
                    int hh = e / D_, dd = e - hh * D_;
                    float cval = acc[mi][ni][r] + bv[ni];
                    size_t bh = (size_t)(b * H_ + hh);
                    if (t == 0)      qo[(bh * N_ + ntok) * D_ + dd] = f2bf(cval * QSCALE_);
                    else if (t == 1) ko[(bh * N_ + ntok) * D_ + dd] = f2bf(cval);
                    else             vo[(bh * D_ + dd) * N_ + ntok] = f2bf(cval);
                }
            }
        }
    }
}

// ---------------------------------------------------------------------------
// Flash attention v3: round-7 kernel with the cross-loop K/V register
// prefetch REMOVED (round-6/7 evidence: +24 live VGPRs vs ~72 budget ->
// scratch spill, WRITE_SIZE 710 MB, dur 290us). Direct global->LDS staging
// (transient regs, round-4 style, zero spill at VGPR 68) + keep: XOR swizzle,
// exp2-domain softmax, defer-max, packed-u32 P shuffles.
// ---------------------------------------------------------------------------
#define QT  64
#define KVT 64
#define NT  (N_ / KVT)

__global__ __launch_bounds__(256) void fattn_kernel(
    const unsigned short* __restrict__ qg, const unsigned short* __restrict__ kg,
    const unsigned short* __restrict__ vtg, unsigned short* __restrict__ out) {
    int bh = blockIdx.y;
    int b = bh >> 3, h = bh & 7;
    int q0 = blockIdx.x * QT;
    int tid = threadIdx.x;
    int l = tid & 63, w = tid >> 6;
    int q16 = l & 15, g = l >> 4;
    int hi2 = (l >> 5) & 1;
    const int swz = (q16 & 7) << 3;          // frag-read swizzle (ushort idx)

    __shared__ __align__(16) unsigned short Qs[QT * D_];    // 12 KB, swizzled
    __shared__ __align__(16) unsigned short Ks[KVT * D_];   // 12 KB, swizzled
    __shared__ __align__(16) unsigned short Vts[D_ * KVT];  // 12 KB, swizzled

    // staging maps
    const int krow = tid >> 2, kc8 = (tid & 3) * 24;   // K/Q: 64 rows x 96
    const int ksw = (krow & 7) << 3;
    const int vrow0 = tid >> 3, vc8 = (tid & 7) * 8;   // V^T: 96 rows x 64

    // ---- stage Q tile once (swizzled) ----
    {
        const uint4* src = (const uint4*)(qg + ((size_t)bh * N_ + q0 + krow) * D_ + kc8);
#pragma unroll
        for (int i = 0; i < 3; ++i)
            *(uint4*)&Qs[(krow * D_ + kc8 + i * 8) ^ ksw] = src[i];
    }
    __syncthreads();

    bf16x8 qf[3];
#pragma unroll
    for (int dc = 0; dc < 3; ++dc)
        qf[dc] = *(const bf16x8*)&Qs[((w * 16 + q16) * D_ + dc * 32 + g * 8) ^ swz];

    float m_run = -INFINITY, l_run = 0.f;
    f32x4 oacc[6] = {};

    for (int kt = 0; kt < NT; ++kt) {
        __syncthreads();   // previous tile's compute done
        // ---- direct global -> LDS staging (transient regs only) ----
        {
            const uint4* ks = (const uint4*)(kg + ((size_t)bh * N_ + kt * KVT + krow) * D_ + kc8);
#pragma unroll
            for (int i = 0; i < 3; ++i)
                *(uint4*)&Ks[(krow * D_ + kc8 + i * 8) ^ ksw] = ks[i];
#pragma unroll
            for (int p = 0; p < 3; ++p) {
                int row = vrow0 + p * 32;
                *(uint4*)&Vts[(row * KVT + vc8) ^ ((row & 7) << 3)] =
                    *(const uint4*)(vtg + ((size_t)bh * D_ + row) * N_ + kt * KVT + vc8);
            }
        }
        __syncthreads();   // tile ready

        // ---- QK^T (swapped): lane holds S^T[kv=sub*16+g*4+r][q=q16] ----
        f32x4 sacc[4] = {};
#pragma unroll
        for (int sub = 0; sub < 4; ++sub)
#pragma unroll
            for (int dc = 0; dc < 3; ++dc) {
                bf16x8 af = *(const bf16x8*)&Ks[((sub * 16 + q16) * D_ + dc * 32 + g * 8) ^ swz];
                sacc[sub] = __builtin_amdgcn_mfma_f32_16x16x32_bf16(af, qf[dc], sacc[sub], 0, 0, 0);
            }

        // ---- online softmax, exp2 domain (log2e folded into q) ----
        float pmax = -INFINITY;
#pragma unroll
        for (int s = 0; s < 4; ++s)
#pragma unroll
            for (int r = 0; r < 4; ++r) pmax = fmaxf(pmax, sacc[s][r]);
        pmax = fmaxf(pmax, __shfl_xor(pmax, 16));
        pmax = fmaxf(pmax, __shfl_xor(pmax, 32));
        if (!__all(pmax - m_run <= 11.0f)) {   // defer-max (T13)
            float m_new = fmaxf(m_run, pmax);
            float fac = exp2f(m_run - m_new);
#pragma unroll
            for (int d = 0; d < 6; ++d)
#pragma unroll
                for (int r = 0; r < 4; ++r) oacc[d][r] *= fac;
            l_run *= fac;
            m_run = m_new;
        }
        float pe[4][4];
        float rs = 0.f;
#pragma unroll
        for (int s = 0; s < 4; ++s)
#pragma unroll
            for (int r = 0; r < 4; ++r) {
                pe[s][r] = exp2f(sacc[s][r] - m_run);
                rs += pe[s][r];
            }
        rs += __shfl_xor(rs, 16);
        rs += __shfl_xor(rs, 32);
        l_run += rs;

        // ---- pack P to bf16 pairs, shuffle u32s into PV B-frag layout ----
        unsigned int pk[4][2];
#pragma unroll
        for (int s = 0; s < 4; ++s)
#pragma unroll
            for (int j = 0; j < 2; ++j)
                pk[s][j] = (unsigned)f2bf_hw(pe[s][2 * j]) |
                           ((unsigned)f2bf_hw(pe[s][2 * j + 1]) << 16);
        union { unsigned int u[4]; bf16x8 v; } pfu[2];
#pragma unroll
        for (int c = 0; c < 2; ++c)
#pragma unroll
            for (int j = 0; j < 4; ++j) {
                int gsrc = (g & 1) * 2 + (j >> 1);
                int src = q16 + (gsrc << 4);
                unsigned a = (unsigned)__shfl((int)pk[c * 2][j & 1], src);
                unsigned bb = (unsigned)__shfl((int)pk[c * 2 + 1][j & 1], src);
                pfu[c].u[j] = hi2 ? bb : a;
            }

        // ---- PV: O^T[dsub] += V^T(16d x 32kv) * P^T(32kv x 16q) ----
#pragma unroll
        for (int dsub = 0; dsub < 6; ++dsub)
#pragma unroll
            for (int c = 0; c < 2; ++c) {
                bf16x8 vf = *(const bf16x8*)&Vts[((dsub * 16 + q16) * KVT + c * 32 + g * 8) ^ swz];
                oacc[dsub] = __builtin_amdgcn_mfma_f32_16x16x32_bf16(vf, pfu[c].v, oacc[dsub], 0, 0, 0);
            }
    }

    // ---- epilogue ----
    float inv = 1.0f / l_run;
    int qrow = q0 + w * 16 + q16;
    size_t base = ((size_t)(b * N_ + qrow)) * E_ + h * D_;
#pragma unroll
    for (int dsub = 0; dsub < 6; ++dsub)
#pragma unroll
        for (int r = 0; r < 4; ++r)
            out[base + dsub * 16 + g * 4 + r] = f2bf_hw(oacc[dsub][r] * inv);
}

// ---------------------------------------------------------------------------
// Orchestration (identical to rounds 4-7).
// ---------------------------------------------------------------------------
extern "C" void kernel_launch(void* const* d_in, const int* in_sizes, int n_in,
                              void* d_out, int out_size, void* d_ws, size_t ws_size,
                              hipStream_t stream) {
    const float* x      = (const float*)d_in[0];
    const float* ln1_g  = (const float*)d_in[1];
    const float* ln1_b  = (const float*)d_in[2];
    const float* qkv_w  = (const float*)d_in[3];
    const float* qkv_b  = (const float*)d_in[4];
    const float* proj_w = (const float*)d_in[5];
    const float* proj_b = (const float*)d_in[6];
    const float* ln2_g  = (const float*)d_in[7];
    const float* ln2_b  = (const float*)d_in[8];
    const float* ff1_w  = (const float*)d_in[9];
    const float* ff1_b  = (const float*)d_in[10];
    const float* ff2_w  = (const float*)d_in[11];
    const float* ff2_b  = (const float*)d_in[12];
    float* out = (float*)d_out;
    float* ws  = (float*)d_ws;

    const size_t S = (size_t)ROWS * E_ / 2;
    unsigned short* qkv_wt = (unsigned short*)ws;
    unsigned short* proj_wt = qkv_wt + (size_t)3 * E_ * E_;
    unsigned short* ff1_wt  = proj_wt + (size_t)E_ * E_;
    unsigned short* ff2_wt  = ff1_wt + (size_t)HID_ * E_;
    float* Rb = ws + 2359296;
    unsigned short* h16   = (unsigned short*)(Rb);
    unsigned short* q16   = (unsigned short*)(Rb + S);
    unsigned short* k16   = (unsigned short*)(Rb + 2 * S);
    unsigned short* vt16  = (unsigned short*)(Rb + 3 * S);
    unsigned short* attnb = h16;
    unsigned short* h16b  = q16;
    unsigned short* ffh   = k16;
    float* x1 = out;

    wcvt_kernel<<<dim3(3 * E_ / 32, E_ / 32), 256, 0, stream>>>(qkv_w, qkv_wt, E_, 3 * E_);
    wcvt_kernel<<<dim3(E_ / 32, E_ / 32), 256, 0, stream>>>(proj_w, proj_wt, E_, E_);
    wcvt_kernel<<<dim3(HID_ / 32, E_ / 32), 256, 0, stream>>>(ff1_w, ff1_wt, E_, HID_);
    wcvt_kernel<<<dim3(E_ / 32, HID_ / 32), 256, 0, stream>>>(ff2_w, ff2_wt, HID_, E_);
    ln_fused_kernel<<<ROWS, 256, 0, stream>>>(x, ln1_g, ln1_b, h16);
    bgemm_kernel<2><<<dim3(3 * E_ / 128, ROWS / 128), 256, 0, stream>>>(
        h16, qkv_wt, qkv_b, nullptr, nullptr, nullptr, q16, k16, vt16,
        ROWS, 3 * E_, E_);
    fattn_kernel<<<dim3(N_ / QT, B_ * H_), 256, 0, stream>>>(q16, k16, vt16, attnb);
    bgemm_kernel<0><<<dim3(E_ / 128, ROWS / 128), 256, 0, stream>>>(
        attnb, proj_wt, proj_b, x, x1, nullptr, nullptr, nullptr, nullptr,
        ROWS, E_, E_);
    ln_fused_kernel<<<ROWS, 256, 0, stream>>>(x1, ln2_g, ln2_b, h16b);
    bgemm_kernel<1><<<dim3(HID_ / 128, ROWS / 128), 256, 0, stream>>>(
        h16b, ff1_wt, ff1_b, nullptr, nullptr, ffh, nullptr, nullptr, nullptr,
        ROWS, HID_, E_);
    bgemm_kernel<0><<<dim3(E_ / 128, ROWS / 128), 256, 0, stream>>>(
        ffh, ff2_wt, ff2_b, x1, out, nullptr, nullptr, nullptr, nullptr,
        ROWS, E_, HID_);
}

// Round 9
// 580.460 us; speedup vs baseline: 1.2981x; 1.0740x over previous
//
#include <hip/hip_runtime.h>
#include <hip/hip_bf16.h>
#include <cstddef>

// Problem constants (fixed by the reference).
#define B_   16
#define N_   1024
#define E_   768
#define H_   8
#define D_   96          // E_/H_
#define HID_ 1536        // 2*E_
#define ROWS (B_ * N_)   // 16384
#define SCALE_  0.03608439182435161f   // 1/sqrt(768)
#define QSCALE_ 0.052058774f           // SCALE_ * log2(e): softmax in exp2 domain

typedef __attribute__((ext_vector_type(8))) short bf16x8;
typedef __attribute__((ext_vector_type(4))) float f32x4;

__device__ __forceinline__ unsigned short f2bf(float f) {
    union { float f; unsigned int u; } c; c.f = f;
    unsigned int u = c.u + 0x7FFFu + ((c.u >> 16) & 1u);  // RNE
    return (unsigned short)(u >> 16);
}

__device__ __forceinline__ unsigned short f2bf_hw(float f) {
    union { __hip_bfloat16 h; unsigned short u; } c;
    c.h = __float2bfloat16(f);
    return c.u;
}

__device__ __forceinline__ void gload16(const void* g, void* l) {
    // async global->LDS, 16B/lane; LDS dest = wave-uniform base + lane*16,
    // global source is PER-LANE (pre-swizzle the source, not the dest).
    __builtin_amdgcn_global_load_lds(
        (const __attribute__((address_space(1))) unsigned int*)g,
        (__attribute__((address_space(3))) unsigned int*)l, 16, 0, 0);
}

__device__ __forceinline__ float gelu_exact(float x) {
    return 0.5f * x * (1.0f + erff(x * 0.7071067811865475f));
}

// ---------------------------------------------------------------------------
// Weight convert+transpose: fp32 W[K][N] -> bf16 Wt[N][K]. 32x32 tiles.
// ---------------------------------------------------------------------------
__global__ __launch_bounds__(256) void wcvt_kernel(const float* __restrict__ W,
                                                   unsigned short* __restrict__ Wt,
                                                   int K, int N) {
    __shared__ float t[32][33];
    int n0 = blockIdx.x * 32, k0 = blockIdx.y * 32;
    int tr = threadIdx.x >> 3;
    int tc = (threadIdx.x & 7) * 4;
    float4 v = *(const float4*)&W[(size_t)(k0 + tr) * N + n0 + tc];
    t[tr][tc + 0] = v.x; t[tr][tc + 1] = v.y; t[tr][tc + 2] = v.z; t[tr][tc + 3] = v.w;
    __syncthreads();
    ushort4 o;
    o.x = f2bf(t[tc + 0][tr]);
    o.y = f2bf(t[tc + 1][tr]);
    o.z = f2bf(t[tc + 2][tr]);
    o.w = f2bf(t[tc + 3][tr]);
    *(ushort4*)&Wt[(size_t)(n0 + tr) * K + k0 + tc] = o;
}

// ---------------------------------------------------------------------------
// Fused LayerNorm -> bf16. One block per row of 768.
// ---------------------------------------------------------------------------
__global__ __launch_bounds__(256) void ln_fused_kernel(const float* __restrict__ x,
                                                       const float* __restrict__ g,
                                                       const float* __restrict__ beta,
                                                       unsigned short* __restrict__ out) {
    int row = blockIdx.x;
    int tid = threadIdx.x;
    const float* xr = x + (size_t)row * E_;
    float v0 = xr[tid];
    float v1 = xr[tid + 256];
    float v2 = xr[tid + 512];
    float s  = v0 + v1 + v2;
    float s2 = v0 * v0 + v1 * v1 + v2 * v2;
#pragma unroll
    for (int off = 32; off > 0; off >>= 1) {
        s  += __shfl_down(s, off);
        s2 += __shfl_down(s2, off);
    }
    __shared__ float sb[8];
    __shared__ float stats[2];
    int lane = tid & 63, wid = tid >> 6;
    if (lane == 0) { sb[wid] = s; sb[4 + wid] = s2; }
    __syncthreads();
    if (tid == 0) {
        float S  = sb[0] + sb[1] + sb[2] + sb[3];
        float S2 = sb[4] + sb[5] + sb[6] + sb[7];
        float m = S * (1.0f / E_);
        float var = S2 * (1.0f / E_) - m * m;
        stats[0] = m;
        stats[1] = rsqrtf(var + 1e-5f);
    }
    __syncthreads();
    float mean = stats[0], rstd = stats[1];
    unsigned short* orow = out + (size_t)row * E_;
    orow[tid]       = f2bf((v0 - mean) * rstd * g[tid]       + beta[tid]);
    orow[tid + 256] = f2bf((v1 - mean) * rstd * g[tid + 256] + beta[tid + 256]);
    orow[tid + 512] = f2bf((v2 - mean) * rstd * g[tid + 512] + beta[tid + 512]);
}

// ---------------------------------------------------------------------------
// bf16 MFMA GEMM (m97 structure) + T1 XCD-aware block remap (all grids %8==0:
// each XCD gets contiguous bm-panels -> A reuse in its private L2).
// MODE2 epilogue (h d t) decode hoisted out of the mi/r loops.
// ---------------------------------------------------------------------------
template<int MODE>
__global__ __launch_bounds__(256) void bgemm_kernel(
    const unsigned short* __restrict__ A, const unsigned short* __restrict__ Wt,
    const float* __restrict__ bias,
    const float* R, float* C, unsigned short* Cb,
    unsigned short* qo, unsigned short* ko, unsigned short* vo,
    int M, int N, int K)
{
    __shared__ __align__(16) unsigned short As[128 * 32];
    __shared__ __align__(16) unsigned short Bs[128 * 32];
    const int tid = threadIdx.x;
    const int l = tid & 63, w = tid >> 6;
    // T1: bijective XCD chunk remap (nwg % 8 == 0 for all four shapes here)
    const int NXg = gridDim.x;
    const int flat = blockIdx.y * NXg + blockIdx.x;
    const int cpx = (NXg * gridDim.y) >> 3;
    const int wid2 = (flat & 7) * cpx + (flat >> 3);
    const int bm = (wid2 / NXg) * 128, bn = (wid2 % NXg) * 128;
    const int wr = (w >> 1) * 64, wc = (w & 1) * 64;
    const int l15 = l & 15, l4 = l >> 4;

    const int srow = w * 16 + (l >> 2);
    const int scol = (l & 3) * 8;
    const unsigned short* Ag = A  + (size_t)(bm + srow) * K + scol;
    const unsigned short* Wg = Wt + (size_t)(bn + srow) * K + scol;
    unsigned short* AsW = As + w * 512;
    unsigned short* BsW = Bs + w * 512;

    f32x4 acc[4][4] = {};

    for (int k0 = 0; k0 < K; k0 += 32) {
        __syncthreads();
        gload16(Ag + k0,                  AsW);
        gload16(Ag + (size_t)64 * K + k0, AsW + 2048);
        gload16(Wg + k0,                  BsW);
        gload16(Wg + (size_t)64 * K + k0, BsW + 2048);
        __syncthreads();
        bf16x8 af[4], bfr[4];
#pragma unroll
        for (int mi = 0; mi < 4; ++mi)
            af[mi] = *(const bf16x8*)&As[(wr + mi * 16 + l15) * 32 + l4 * 8];
#pragma unroll
        for (int ni = 0; ni < 4; ++ni)
            bfr[ni] = *(const bf16x8*)&Bs[(wc + ni * 16 + l15) * 32 + l4 * 8];
#pragma unroll
        for (int mi = 0; mi < 4; ++mi)
#pragma unroll
            for (int ni = 0; ni < 4; ++ni)
                acc[mi][ni] = __builtin_amdgcn_mfma_f32_16x16x32_bf16(
                    af[mi], bfr[ni], acc[mi][ni], 0, 0, 0);
    }

    const int r0 = bm + wr + l4 * 4;
    const int c0 = bn + wc + l15;
    float bv[4];
#pragma unroll
    for (int ni = 0; ni < 4; ++ni) bv[ni] = bias[c0 + ni * 16];

    // MODE2: hoist the (h d t) column decode (per-ni constants)
    int e4[4], t4[4], hh4[4], dd4[4];
    if constexpr (MODE == 2) {
#pragma unroll
        for (int ni = 0; ni < 4; ++ni) {
            int n = c0 + ni * 16;
            e4[ni] = n / 3; t4[ni] = n - e4[ni] * 3;
            hh4[ni] = e4[ni] / D_; dd4[ni] = e4[ni] - hh4[ni] * D_;
        }
    }

#pragma unroll
    for (int mi = 0; mi < 4; ++mi) {
#pragma unroll
        for (int r = 0; r < 4; ++r) {
            int row = r0 + mi * 16 + r;
            if constexpr (MODE == 0) {
                size_t base = (size_t)row * N;
#pragma unroll
                for (int ni = 0; ni < 4; ++ni) {
                    size_t idx = base + c0 + ni * 16;
                    C[idx] = acc[mi][ni][r] + bv[ni] + R[idx];
                }
            } else if constexpr (MODE == 1) {
                size_t base = (size_t)row * N;
#pragma unroll
                for (int ni = 0; ni < 4; ++ni) {
                    size_t idx = base + c0 + ni * 16;
                    Cb[idx] = f2bf(gelu_exact(acc[mi][ni][r] + bv[ni]));
                }
            } else {
                int b = row >> 10, ntok = row & (N_ - 1);
#pragma unroll
                for (int ni = 0; ni < 4; ++ni) {
                    float cval = acc[mi][ni][r] + bv[ni];
                    size_t bh = (size_t)(b * H_ + hh4[ni]);
                    if (t4[ni] == 0)      qo[(bh * N_ + ntok) * D_ + dd4[ni]] = f2bf(cval * QSCALE_);
                    else if (t4[ni] == 1) ko[(bh * N_ + ntok) * D_ + dd4[ni]] = f2bf(cval);
                    else                  vo[(bh * D_ + dd4[ni]) * N_ + ntok] = f2bf(cval);
                }
            }
        }
    }
}

// ---------------------------------------------------------------------------
// Flash attention v4: K/V staging via async global_load_lds with PRE-SWIZZLED
// per-lane SOURCE addresses (rule #21 / m173) — removes the reg round-trip and
// staging VALU of v3. K uses a padded [64][16-slot] LDS layout (16 KB; 4 pad
// slots/row fetch clamped-valid junk, never read) so the XOR swizzle stays
// closed per row under the linear DMA dest. V^T rows are 8 slots -> swizzle
// closed naturally. Q staging/reads unchanged. + T5 setprio around MFMA.
// LDS 40 KB -> 4 blocks/CU.
// ---------------------------------------------------------------------------
#define QT  64
#define KVT 64
#define NT  (N_ / KVT)

__global__ __launch_bounds__(256) void fattn_kernel(
    const unsigned short* __restrict__ qg, const unsigned short* __restrict__ kg,
    const unsigned short* __restrict__ vtg, unsigned short* __restrict__ out) {
    int bh = blockIdx.y;
    int b = bh >> 3, h = bh & 7;
    int q0 = blockIdx.x * QT;
    int tid = threadIdx.x;
    int l = tid & 63, w = tid >> 6;
    int q16 = l & 15, g = l >> 4;
    int hi2 = (l >> 5) & 1;
    const int swz = (q16 & 7) << 3;          // Q/V frag-read swizzle (flat XOR)

    __shared__ __align__(16) unsigned short Qs[QT * D_];     // 12 KB (96-col rows)
    __shared__ __align__(16) unsigned short Ks[KVT * 128];   // 16 KB padded (16 slots/row)
    __shared__ __align__(16) unsigned short Vts[D_ * KVT];   // 12 KB (64-col rows)

    // ---- stage Q tile once (reg path, swizzled; as in v3) ----
    {
        int krow = tid >> 2, kc8 = (tid & 3) * 24;
        int ksw = (krow & 7) << 3;
        const uint4* src = (const uint4*)(qg + ((size_t)bh * N_ + q0 + krow) * D_ + kc8);
#pragma unroll
        for (int i = 0; i < 3; ++i)
            *(uint4*)&Qs[(krow * D_ + kc8 + i * 8) ^ ksw] = src[i];
    }

    // ---- per-lane pre-swizzled global source bases for K/V DMA ----
    // K: dest region r=w*4+i covers rows r*4..r*4+3 (16 slots each);
    //    lane -> row = r*4 + (l>>4), destslot = l&15, src col8 = destslot ^ (row&7)
    const unsigned short* kbase[4];
#pragma unroll
    for (int i = 0; i < 4; ++i) {
        int r = w * 4 + i;
        int rowK = r * 4 + (l >> 4);
        int c8 = (l & 15) ^ (rowK & 7);
        if (c8 >= 12) c8 = 0;                 // pad slot: clamp to in-range junk
        kbase[i] = kg + ((size_t)bh * N_ + rowK) * D_ + c8 * 8;
    }
    // V: dest region r=w*3+i covers rows r*8..r*8+7 (8 slots each);
    //    lane -> row = r*8 + (l>>3), destslot = l&7, src col8 = destslot ^ (row&7)
    const unsigned short* vbase[3];
#pragma unroll
    for (int i = 0; i < 3; ++i) {
        int r = w * 3 + i;
        int rowV = r * 8 + (l >> 3);
        int c8 = (l & 7) ^ (rowV & 7);
        vbase[i] = vtg + ((size_t)bh * D_ + rowV) * N_ + c8 * 8;
    }

    __syncthreads();   // Q staged

    bf16x8 qf[3];
#pragma unroll
    for (int dc = 0; dc < 3; ++dc)
        qf[dc] = *(const bf16x8*)&Qs[((w * 16 + q16) * D_ + dc * 32 + g * 8) ^ swz];

    float m_run = -INFINITY, l_run = 0.f;
    f32x4 oacc[6] = {};

    for (int kt = 0; kt < NT; ++kt) {
        __syncthreads();   // previous tile's compute done (LDS free)
        // ---- async DMA staging: 7 global_load_lds, zero reg round-trip ----
#pragma unroll
        for (int i = 0; i < 4; ++i)
            gload16(kbase[i] + (size_t)kt * KVT * D_, Ks + (w * 4 + i) * 512);
#pragma unroll
        for (int i = 0; i < 3; ++i)
            gload16(vbase[i] + (size_t)kt * KVT, Vts + (w * 3 + i) * 512);
        __syncthreads();   // drains vmcnt: tile ready

        // ---- QK^T (swapped): lane holds S^T[kv=sub*16+g*4+r][q=q16] ----
        f32x4 sacc[4] = {};
        __builtin_amdgcn_s_setprio(1);
#pragma unroll
        for (int sub = 0; sub < 4; ++sub)
#pragma unroll
            for (int dc = 0; dc < 3; ++dc) {
                bf16x8 af = *(const bf16x8*)&Ks[(sub * 16 + q16) * 128 +
                                                (((dc << 2) + g) ^ (q16 & 7)) * 8];
                sacc[sub] = __builtin_amdgcn_mfma_f32_16x16x32_bf16(af, qf[dc], sacc[sub], 0, 0, 0);
            }
        __builtin_amdgcn_s_setprio(0);

        // ---- online softmax, exp2 domain (log2e folded into q) ----
        float pmax = -INFINITY;
#pragma unroll
        for (int s = 0; s < 4; ++s)
#pragma unroll
            for (int r = 0; r < 4; ++r) pmax = fmaxf(pmax, sacc[s][r]);
        pmax = fmaxf(pmax, __shfl_xor(pmax, 16));
        pmax = fmaxf(pmax, __shfl_xor(pmax, 32));
        if (!__all(pmax - m_run <= 11.0f)) {   // defer-max (T13)
            float m_new = fmaxf(m_run, pmax);
            float fac = exp2f(m_run - m_new);
#pragma unroll
            for (int d = 0; d < 6; ++d)
#pragma unroll
                for (int r = 0; r < 4; ++r) oacc[d][r] *= fac;
            l_run *= fac;
            m_run = m_new;
        }
        float pe[4][4];
        float rs = 0.f;
#pragma unroll
        for (int s = 0; s < 4; ++s)
#pragma unroll
            for (int r = 0; r < 4; ++r) {
                pe[s][r] = exp2f(sacc[s][r] - m_run);
                rs += pe[s][r];
            }
        rs += __shfl_xor(rs, 16);
        rs += __shfl_xor(rs, 32);
        l_run += rs;

        // ---- pack P to bf16 pairs, shuffle u32s into PV B-frag layout ----
        unsigned int pk[4][2];
#pragma unroll
        for (int s = 0; s < 4; ++s)
#pragma unroll
            for (int j = 0; j < 2; ++j)
                pk[s][j] = (unsigned)f2bf_hw(pe[s][2 * j]) |
                           ((unsigned)f2bf_hw(pe[s][2 * j + 1]) << 16);
        union { unsigned int u[4]; bf16x8 v; } pfu[2];
#pragma unroll
        for (int c = 0; c < 2; ++c)
#pragma unroll
            for (int j = 0; j < 4; ++j) {
                int gsrc = (g & 1) * 2 + (j >> 1);
                int src = q16 + (gsrc << 4);
                unsigned a = (unsigned)__shfl((int)pk[c * 2][j & 1], src);
                unsigned bb = (unsigned)__shfl((int)pk[c * 2 + 1][j & 1], src);
                pfu[c].u[j] = hi2 ? bb : a;
            }

        // ---- PV: O^T[dsub] += V^T(16d x 32kv) * P^T(32kv x 16q) ----
        __builtin_amdgcn_s_setprio(1);
#pragma unroll
        for (int dsub = 0; dsub < 6; ++dsub)
#pragma unroll
            for (int c = 0; c < 2; ++c) {
                bf16x8 vf = *(const bf16x8*)&Vts[((dsub * 16 + q16) * KVT + c * 32 + g * 8) ^ swz];
                oacc[dsub] = __builtin_amdgcn_mfma_f32_16x16x32_bf16(vf, pfu[c].v, oacc[dsub], 0, 0, 0);
            }
        __builtin_amdgcn_s_setprio(0);
    }

    // ---- epilogue ----
    float inv = 1.0f / l_run;
    int qrow = q0 + w * 16 + q16;
    size_t base = ((size_t)(b * N_ + qrow)) * E_ + h * D_;
#pragma unroll
    for (int dsub = 0; dsub < 6; ++dsub)
#pragma unroll
        for (int r = 0; r < 4; ++r)
            out[base + dsub * 16 + g * 4 + r] = f2bf_hw(oacc[dsub][r] * inv);
}

// ---------------------------------------------------------------------------
// Orchestration (identical to rounds 4-8).
// ---------------------------------------------------------------------------
extern "C" void kernel_launch(void* const* d_in, const int* in_sizes, int n_in,
                              void* d_out, int out_size, void* d_ws, size_t ws_size,
                              hipStream_t stream) {
    const float* x      = (const float*)d_in[0];
    const float* ln1_g  = (const float*)d_in[1];
    const float* ln1_b  = (const float*)d_in[2];
    const float* qkv_w  = (const float*)d_in[3];
    const float* qkv_b  = (const float*)d_in[4];
    const float* proj_w = (const float*)d_in[5];
    const float* proj_b = (const float*)d_in[6];
    const float* ln2_g  = (const float*)d_in[7];
    const float* ln2_b  = (const float*)d_in[8];
    const float* ff1_w  = (const float*)d_in[9];
    const float* ff1_b  = (const float*)d_in[10];
    const float* ff2_w  = (const float*)d_in[11];
    const float* ff2_b  = (const float*)d_in[12];
    float* out = (float*)d_out;
    float* ws  = (float*)d_ws;

    const size_t S = (size_t)ROWS * E_ / 2;
    unsigned short* qkv_wt = (unsigned short*)ws;
    unsigned short* proj_wt = qkv_wt + (size_t)3 * E_ * E_;
    unsigned short* ff1_wt  = proj_wt + (size_t)E_ * E_;
    unsigned short* ff2_wt  = ff1_wt + (size_t)HID_ * E_;
    float* Rb = ws + 2359296;
    unsigned short* h16   = (unsigned short*)(Rb);
    unsigned short* q16   = (unsigned short*)(Rb + S);
    unsigned short* k16   = (unsigned short*)(Rb + 2 * S);
    unsigned short* vt16  = (unsigned short*)(Rb + 3 * S);
    unsigned short* attnb = h16;
    unsigned short* h16b  = q16;
    unsigned short* ffh   = k16;
    float* x1 = out;

    wcvt_kernel<<<dim3(3 * E_ / 32, E_ / 32), 256, 0, stream>>>(qkv_w, qkv_wt, E_, 3 * E_);
    wcvt_kernel<<<dim3(E_ / 32, E_ / 32), 256, 0, stream>>>(proj_w, proj_wt, E_, E_);
    wcvt_kernel<<<dim3(HID_ / 32, E_ / 32), 256, 0, stream>>>(ff1_w, ff1_wt, E_, HID_);
    wcvt_kernel<<<dim3(E_ / 32, HID_ / 32), 256, 0, stream>>>(ff2_w, ff2_wt, HID_, E_);
    ln_fused_kernel<<<ROWS, 256, 0, stream>>>(x, ln1_g, ln1_b, h16);
    bgemm_kernel<2><<<dim3(3 * E_ / 128, ROWS / 128), 256, 0, stream>>>(
        h16, qkv_wt, qkv_b, nullptr, nullptr, nullptr, q16, k16, vt16,
        ROWS, 3 * E_, E_);
    fattn_kernel<<<dim3(N_ / QT, B_ * H_), 256, 0, stream>>>(q16, k16, vt16, attnb);
    bgemm_kernel<0><<<dim3(E_ / 128, ROWS / 128), 256, 0, stream>>>(
        attnb, proj_wt, proj_b, x, x1, nullptr, nullptr, nullptr, nullptr,
        ROWS, E_, E_);
    ln_fused_kernel<<<ROWS, 256, 0, stream>>>(x1, ln2_g, ln2_b, h16b);
    bgemm_kernel<1><<<dim3(HID_ / 128, ROWS / 128), 256, 0, stream>>>(
        h16b, ff1_wt, ff1_b, nullptr, nullptr, ffh, nullptr, nullptr, nullptr,
        ROWS, HID_, E_);
    bgemm_kernel<0><<<dim3(E_ / 128, ROWS / 128), 256, 0, stream>>>(
        ffh, ff2_wt, ff2_b, x1, out, nullptr, nullptr, nullptr, nullptr,
        ROWS, E_, HID_);
}